// Round 1
// baseline (417.921 us; speedup 1.0000x reference)
//
#include <hip/hip_runtime.h>
#include <hip/hip_bf16.h>

typedef __attribute__((ext_vector_type(8))) short bf16x8;
typedef __attribute__((ext_vector_type(4))) float f32x4;
typedef __attribute__((ext_vector_type(4))) unsigned short u16x4;
typedef __attribute__((ext_vector_type(8))) unsigned short u16x8;

#define DEVI static __device__ __forceinline__

DEVI unsigned short f2bf(float f) {
  union { __hip_bfloat16 h; unsigned short u; } cv;
  cv.h = __float2bfloat16(f);
  return cv.u;
}

DEVI void gld_lds16(const unsigned short* g, unsigned short* l) {
  __builtin_amdgcn_global_load_lds(
      (const __attribute__((address_space(1))) unsigned int*)g,
      (__attribute__((address_space(3))) unsigned int*)l, 16, 0, 0);
}

// ---------------- prep kernels ----------------

// batch f32 -> bf16, 4 elems/thread. grid*256*4 == 4096*1024 exactly.
__global__ void k_cvt_x(const float* __restrict__ x, unsigned short* __restrict__ xb) {
  int i = blockIdx.x * 256 + threadIdx.x;
  f32x4 v = *((const f32x4*)x + i);
  u16x4 o;
#pragma unroll
  for (int j = 0; j < 4; ++j) o[j] = f2bf(v[j]);
  *((u16x4*)xb + i) = o;
}

// W[g][k][n] f32 -> Wt[g][n][k] bf16 via 32x32 LDS tiles. 4096 blocks.
__global__ void k_wt(const float* __restrict__ Wq, const float* __restrict__ Wk,
                     const float* __restrict__ Wv, const float* __restrict__ Wo,
                     unsigned short* __restrict__ wqkvT, unsigned short* __restrict__ woT) {
  __shared__ float lt[32][33];
  int t = blockIdx.x;
  int g = t >> 10, r = t & 1023, kt = r >> 5, nt = r & 31;
  const float* W = (g == 0) ? Wq : (g == 1) ? Wk : (g == 2) ? Wv : Wo;
  unsigned short* out = (g < 3) ? (wqkvT + (size_t)g * 1024 * 1024) : woT;
  int tid = threadIdx.x;
  int row = tid >> 3, c4 = tid & 7;
  f32x4 v = *(const f32x4*)(W + (size_t)(kt * 32 + row) * 1024 + nt * 32 + c4 * 4);
#pragma unroll
  for (int j = 0; j < 4; ++j) lt[row][c4 * 4 + j] = v[j];
  __syncthreads();
  u16x4 o;
#pragma unroll
  for (int j = 0; j < 4; ++j) o[j] = f2bf(lt[c4 * 4 + j][row]);
  *(u16x4*)(out + (size_t)(nt * 32 + row) * 1024 + kt * 32 + c4 * 4) = o;
}

__global__ void k_bias(const float* __restrict__ bq, const float* __restrict__ bk,
                       const float* __restrict__ bv, float* __restrict__ bcat) {
  int i = blockIdx.x * 256 + threadIdx.x;
  if (i < 3072) bcat[i] = (i < 1024) ? bq[i] : (i < 2048) ? bk[i - 1024] : bv[i - 2048];
}

// transpose V slice of QKV -> Vt[(b*16+h)*64 + d][s]  (bf16)
__global__ void k_vt(const unsigned short* __restrict__ qkv, unsigned short* __restrict__ vt) {
  __shared__ unsigned short lt[64][72];
  int bh = blockIdx.y, s0 = blockIdx.x * 64;
  int b = bh >> 4, h = bh & 15;
  int tid = threadIdx.x;
#pragma unroll
  for (int i = 0; i < 2; ++i) {
    int c = tid + i * 256;
    int row = c >> 3, c8 = (c & 7) * 8;
    u16x8 v = *(const u16x8*)(qkv + (size_t)(b * 2048 + s0 + row) * 3072 + 2048 + h * 64 + c8);
#pragma unroll
    for (int j = 0; j < 8; ++j) lt[row][c8 + j] = v[j];
  }
  __syncthreads();
#pragma unroll
  for (int i = 0; i < 2; ++i) {
    int c = tid + i * 256;
    int d = c >> 3, s8 = (c & 7) * 8;
    u16x8 o;
#pragma unroll
    for (int j = 0; j < 8; ++j) o[j] = lt[s8 + j][d];
    *(u16x8*)(vt + (size_t)(bh * 64 + d) * 2048 + s0 + s8) = o;
  }
}

// ---------------- GEMM: C[M][N] = A[M][K](bf16) @ Bt[N][K](bf16)^T + bias ----------------
// m97 structure: 128x128 tile, BK=32, 4 waves (2x2), 4x4 16x16x32 frags per wave.
template <int OUT_BF16>
__launch_bounds__(256)
__global__ void k_gemm(const unsigned short* __restrict__ A,
                       const unsigned short* __restrict__ Bt,
                       const float* __restrict__ bias, void* __restrict__ C,
                       int M, int N, int K) {
  __shared__ unsigned short lA[128 * 32];
  __shared__ unsigned short lB[128 * 32];
  int tid = threadIdx.x;
  int m0 = blockIdx.y * 128, n0 = blockIdx.x * 128;
  int w = tid >> 6, l = tid & 63;
  int wm = (w >> 1) * 64, wn = (w & 1) * 64;
  int lg = l >> 4, lc = l & 15;
  f32x4 acc[4][4] = {};
  const unsigned short* Ab = A + (size_t)m0 * K;
  const unsigned short* Bb = Bt + (size_t)n0 * K;

  for (int kk = 0; kk < K; kk += 32) {
#pragma unroll
    for (int i = 0; i < 2; ++i) {
      int c = tid + i * 256;
      int row = c >> 2, c8 = (c & 3) * 8;
      gld_lds16(Ab + (size_t)row * K + kk + c8, lA + c * 8);
    }
#pragma unroll
    for (int i = 0; i < 2; ++i) {
      int c = tid + i * 256;
      int row = c >> 2, c8 = (c & 3) * 8;
      gld_lds16(Bb + (size_t)row * K + kk + c8, lB + c * 8);
    }
    __syncthreads();
    bf16x8 af[4], bfr[4];
#pragma unroll
    for (int mf = 0; mf < 4; ++mf)
      af[mf] = *(const bf16x8*)(lA + (wm + mf * 16 + lc) * 32 + lg * 8);
#pragma unroll
    for (int nf = 0; nf < 4; ++nf)
      bfr[nf] = *(const bf16x8*)(lB + (wn + nf * 16 + lc) * 32 + lg * 8);
#pragma unroll
    for (int mf = 0; mf < 4; ++mf)
#pragma unroll
      for (int nf = 0; nf < 4; ++nf)
        acc[mf][nf] = __builtin_amdgcn_mfma_f32_16x16x32_bf16(af[mf], bfr[nf], acc[mf][nf], 0, 0, 0);
    __syncthreads();
  }

  int lr = lg * 4;
  float bv[4];
#pragma unroll
  for (int nf = 0; nf < 4; ++nf) bv[nf] = bias[n0 + wn + nf * 16 + lc];
#pragma unroll
  for (int mf = 0; mf < 4; ++mf)
#pragma unroll
    for (int nf = 0; nf < 4; ++nf)
#pragma unroll
      for (int rr = 0; rr < 4; ++rr) {
        size_t gm = m0 + wm + mf * 16 + lr + rr;
        size_t gn = n0 + wn + nf * 16 + lc;
        float v = acc[mf][nf][rr] + bv[nf];
        if (OUT_BF16)
          ((unsigned short*)C)[gm * N + gn] = f2bf(v);
        else
          ((float*)C)[gm * N + gn] = v;
      }
}

// ---------------- flash attention ----------------
// grid: 1024 wgs = b(2) x h(16) x qtile(32).  4 waves/wg, 16 q-rows/wave, KVBLK=64.
__launch_bounds__(256)
__global__ void k_attn(const unsigned short* __restrict__ qkv,
                       const unsigned short* __restrict__ vt,
                       const float* __restrict__ mask,
                       unsigned short* __restrict__ ao) {
  __shared__ unsigned short lP[64][72];
  int wg = blockIdx.x;
  int b = wg >> 9, r0 = wg & 511, h = r0 >> 5, qt = r0 & 31;
  int tid = threadIdx.x, w = tid >> 6, l = tid & 63;
  int lg = l >> 4, lc = l & 15;
  int q0 = qt * 64 + w * 16;  // batch-local q base of this wave

  const unsigned short* Qb = qkv + (size_t)(b * 2048 + q0) * 3072 + h * 64;
  const unsigned short* Kb = qkv + (size_t)(b * 2048) * 3072 + 1024 + h * 64;
  const unsigned short* Vb = vt + (size_t)((b * 16 + h) * 64) * 2048;

  bf16x8 qf[2];
#pragma unroll
  for (int ks = 0; ks < 2; ++ks)
    qf[ks] = *(const bf16x8*)(Qb + (size_t)lc * 3072 + ks * 32 + lg * 8);

  f32x4 o[4] = {};
  float m[4], ll[4];
#pragma unroll
  for (int rr = 0; rr < 4; ++rr) { m[rr] = -1e30f; ll[rr] = 0.f; }

  for (int k0 = 0; k0 < 2048; k0 += 64) {
    // S = Q @ K^T   (K frags direct from global, L2-resident)
    bf16x8 kf[2][4];
#pragma unroll
    for (int ks = 0; ks < 2; ++ks)
#pragma unroll
      for (int nf = 0; nf < 4; ++nf)
        kf[ks][nf] = *(const bf16x8*)(Kb + (size_t)(k0 + nf * 16 + lc) * 3072 + ks * 32 + lg * 8);
    f32x4 s[4] = {};
#pragma unroll
    for (int ks = 0; ks < 2; ++ks)
#pragma unroll
      for (int nf = 0; nf < 4; ++nf)
        s[nf] = __builtin_amdgcn_mfma_f32_16x16x32_bf16(qf[ks], kf[ks][nf], s[nf], 0, 0, 0);

    // V frags: issue early, consumed after softmax
    bf16x8 vf[2][4];
#pragma unroll
    for (int ks = 0; ks < 2; ++ks)
#pragma unroll
      for (int nf = 0; nf < 4; ++nf)
        vf[ks][nf] = *(const bf16x8*)(Vb + (size_t)(nf * 16 + lc) * 2048 + k0 + ks * 32 + lg * 8);

    // scale + mask
    float sv[4][4];
#pragma unroll
    for (int nf = 0; nf < 4; ++nf)
#pragma unroll
      for (int rr = 0; rr < 4; ++rr)
        sv[nf][rr] = s[nf][rr] * 0.125f +
                     mask[(size_t)(q0 + lg * 4 + rr) * 2048 + k0 + nf * 16 + lc];

    // online softmax
    float al[4], mn[4];
#pragma unroll
    for (int rr = 0; rr < 4; ++rr) {
      float t = fmaxf(fmaxf(sv[0][rr], sv[1][rr]), fmaxf(sv[2][rr], sv[3][rr]));
      t = fmaxf(t, __shfl_xor(t, 1));
      t = fmaxf(t, __shfl_xor(t, 2));
      t = fmaxf(t, __shfl_xor(t, 4));
      t = fmaxf(t, __shfl_xor(t, 8));
      mn[rr] = fmaxf(m[rr], t);
      al[rr] = __expf(m[rr] - mn[rr]);
      m[rr] = mn[rr];
    }
    float ps[4] = {0.f, 0.f, 0.f, 0.f};
#pragma unroll
    for (int nf = 0; nf < 4; ++nf)
#pragma unroll
      for (int rr = 0; rr < 4; ++rr) {
        float p = __expf(sv[nf][rr] - mn[rr]);
        ps[rr] += p;
        lP[w * 16 + lg * 4 + rr][nf * 16 + lc] = f2bf(p);
      }
#pragma unroll
    for (int rr = 0; rr < 4; ++rr) {
      float t = ps[rr];
      t += __shfl_xor(t, 1);
      t += __shfl_xor(t, 2);
      t += __shfl_xor(t, 4);
      t += __shfl_xor(t, 8);
      ll[rr] = ll[rr] * al[rr] + t;
    }
#pragma unroll
    for (int nf = 0; nf < 4; ++nf)
#pragma unroll
      for (int rr = 0; rr < 4; ++rr) o[nf][rr] *= al[rr];

    // O += P @ V   (P via wave-private LDS slice; compiler orders write->read)
#pragma unroll
    for (int ks2 = 0; ks2 < 2; ++ks2) {
      bf16x8 pa = *(const bf16x8*)(&lP[w * 16 + lc][ks2 * 32 + lg * 8]);
#pragma unroll
      for (int nf = 0; nf < 4; ++nf)
        o[nf] = __builtin_amdgcn_mfma_f32_16x16x32_bf16(pa, vf[ks2][nf], o[nf], 0, 0, 0);
    }
  }

#pragma unroll
  for (int rr = 0; rr < 4; ++rr) {
    float inv = 1.f / ll[rr];
    int q = q0 + lg * 4 + rr;
#pragma unroll
    for (int nf = 0; nf < 4; ++nf)
      ao[(size_t)(b * 2048 + q) * 1024 + h * 64 + nf * 16 + lc] = f2bf(o[nf][rr] * inv);
  }
}

// ---------------- launch ----------------
extern "C" void kernel_launch(void* const* d_in, const int* in_sizes, int n_in,
                              void* d_out, int out_size, void* d_ws, size_t ws_size,
                              hipStream_t stream) {
  const float* batch = (const float*)d_in[0];
  const float* mask = (const float*)d_in[1];
  const float* Wq = (const float*)d_in[2];
  const float* Wk = (const float*)d_in[3];
  const float* Wv = (const float*)d_in[4];
  const float* bq = (const float*)d_in[5];
  const float* bk = (const float*)d_in[6];
  const float* bvv = (const float*)d_in[7];
  const float* Wo = (const float*)d_in[8];
  const float* bo = (const float*)d_in[9];

  char* ws = (char*)d_ws;
  unsigned short* Xb    = (unsigned short*)(ws);                 //  8,388,608
  unsigned short* WqkvT = (unsigned short*)(ws + 8388608);       //  6,291,456
  unsigned short* WoT   = (unsigned short*)(ws + 14680064);      //  2,097,152
  float*          bcat  = (float*)(ws + 16777216);               //     12,288
  unsigned short* QKV   = (unsigned short*)(ws + 16789504);      // 25,165,824
  unsigned short* Vt    = (unsigned short*)(ws + 41955328);      //  8,388,608
  unsigned short* AO    = (unsigned short*)(ws + 50343936);      //  8,388,608

  hipLaunchKernelGGL(k_cvt_x, dim3(4096), dim3(256), 0, stream, batch, Xb);
  hipLaunchKernelGGL(k_wt, dim3(4096), dim3(256), 0, stream, Wq, Wk, Wv, Wo, WqkvT, WoT);
  hipLaunchKernelGGL(k_bias, dim3(12), dim3(256), 0, stream, bq, bk, bvv, bcat);
  hipLaunchKernelGGL((k_gemm<1>), dim3(24, 32), dim3(256), 0, stream,
                     Xb, WqkvT, bcat, (void*)QKV, 4096, 3072, 1024);
  hipLaunchKernelGGL(k_vt, dim3(32, 32), dim3(256), 0, stream, QKV, Vt);
  hipLaunchKernelGGL(k_attn, dim3(1024), dim3(256), 0, stream, QKV, Vt, mask, AO);
  hipLaunchKernelGGL((k_gemm<0>), dim3(8, 32), dim3(256), 0, stream,
                     AO, WoT, bo, (void*)d_out, 4096, 1024, 1024);
}

// Round 2
// 279.757 us; speedup vs baseline: 1.4939x; 1.4939x over previous
//
#include <hip/hip_runtime.h>
#include <hip/hip_bf16.h>

typedef __attribute__((ext_vector_type(8))) short bf16x8;
typedef __attribute__((ext_vector_type(4))) float f32x4;
typedef __attribute__((ext_vector_type(4))) unsigned short u16x4;
typedef __attribute__((ext_vector_type(8))) unsigned short u16x8;

#define DEVI static __device__ __forceinline__

DEVI unsigned short f2bf(float f) {
  union { __hip_bfloat16 h; unsigned short u; } cv;
  cv.h = __float2bfloat16(f);
  return cv.u;
}

DEVI void gld_lds16(const unsigned short* g, unsigned short* l) {
  __builtin_amdgcn_global_load_lds(
      (const __attribute__((address_space(1))) unsigned int*)g,
      (__attribute__((address_space(3))) unsigned int*)l, 16, 0, 0);
}

// ---------------- prep kernels ----------------

// batch f32 -> bf16, 4 elems/thread. grid*256*4 == 4096*1024 exactly.
__global__ void k_cvt_x(const float* __restrict__ x, unsigned short* __restrict__ xb) {
  int i = blockIdx.x * 256 + threadIdx.x;
  f32x4 v = *((const f32x4*)x + i);
  u16x4 o;
#pragma unroll
  for (int j = 0; j < 4; ++j) o[j] = f2bf(v[j]);
  *((u16x4*)xb + i) = o;
}

// W[g][k][n] f32 -> Wt[g][n][k] bf16 via 32x32 LDS tiles. 4096 blocks.
__global__ void k_wt(const float* __restrict__ Wq, const float* __restrict__ Wk,
                     const float* __restrict__ Wv, const float* __restrict__ Wo,
                     unsigned short* __restrict__ wqkvT, unsigned short* __restrict__ woT) {
  __shared__ float lt[32][33];
  int t = blockIdx.x;
  int g = t >> 10, r = t & 1023, kt = r >> 5, nt = r & 31;
  const float* W = (g == 0) ? Wq : (g == 1) ? Wk : (g == 2) ? Wv : Wo;
  unsigned short* out = (g < 3) ? (wqkvT + (size_t)g * 1024 * 1024) : woT;
  int tid = threadIdx.x;
  int row = tid >> 3, c4 = tid & 7;
  f32x4 v = *(const f32x4*)(W + (size_t)(kt * 32 + row) * 1024 + nt * 32 + c4 * 4);
#pragma unroll
  for (int j = 0; j < 4; ++j) lt[row][c4 * 4 + j] = v[j];
  __syncthreads();
  u16x4 o;
#pragma unroll
  for (int j = 0; j < 4; ++j) o[j] = f2bf(lt[c4 * 4 + j][row]);
  *(u16x4*)(out + (size_t)(nt * 32 + row) * 1024 + kt * 32 + c4 * 4) = o;
}

__global__ void k_bias(const float* __restrict__ bq, const float* __restrict__ bk,
                       const float* __restrict__ bv, float* __restrict__ bcat) {
  int i = blockIdx.x * 256 + threadIdx.x;
  if (i < 3072) bcat[i] = (i < 1024) ? bq[i] : (i < 2048) ? bk[i - 1024] : bv[i - 2048];
}

// transpose V slice of QKV -> Vt[(b*16+h)*64 + d][s]  (bf16)
__global__ void k_vt(const unsigned short* __restrict__ qkv, unsigned short* __restrict__ vt) {
  __shared__ unsigned short lt[64][72];
  int bh = blockIdx.y, s0 = blockIdx.x * 64;
  int b = bh >> 4, h = bh & 15;
  int tid = threadIdx.x;
#pragma unroll
  for (int i = 0; i < 2; ++i) {
    int c = tid + i * 256;
    int row = c >> 3, c8 = (c & 7) * 8;
    u16x8 v = *(const u16x8*)(qkv + (size_t)(b * 2048 + s0 + row) * 3072 + 2048 + h * 64 + c8);
#pragma unroll
    for (int j = 0; j < 8; ++j) lt[row][c8 + j] = v[j];
  }
  __syncthreads();
#pragma unroll
  for (int i = 0; i < 2; ++i) {
    int c = tid + i * 256;
    int d = c >> 3, s8 = (c & 7) * 8;
    u16x8 o;
#pragma unroll
    for (int j = 0; j < 8; ++j) o[j] = lt[s8 + j][d];
    *(u16x8*)(vt + (size_t)(bh * 64 + d) * 2048 + s0 + s8) = o;
  }
}

// ---------------- GEMM: C[M][N] = A[M][K](bf16) @ Bt[N][K](bf16)^T + bias ----------------
template <int OUT_BF16>
__launch_bounds__(256)
__global__ void k_gemm(const unsigned short* __restrict__ A,
                       const unsigned short* __restrict__ Bt,
                       const float* __restrict__ bias, void* __restrict__ C,
                       int M, int N, int K) {
  __shared__ unsigned short lA[128 * 32];
  __shared__ unsigned short lB[128 * 32];
  int tid = threadIdx.x;
  int m0 = blockIdx.y * 128, n0 = blockIdx.x * 128;
  int w = tid >> 6, l = tid & 63;
  int wm = (w >> 1) * 64, wn = (w & 1) * 64;
  int lg = l >> 4, lc = l & 15;
  f32x4 acc[4][4] = {};
  const unsigned short* Ab = A + (size_t)m0 * K;
  const unsigned short* Bb = Bt + (size_t)n0 * K;

  for (int kk = 0; kk < K; kk += 32) {
#pragma unroll
    for (int i = 0; i < 2; ++i) {
      int c = tid + i * 256;
      int row = c >> 2, c8 = (c & 3) * 8;
      gld_lds16(Ab + (size_t)row * K + kk + c8, lA + c * 8);
    }
#pragma unroll
    for (int i = 0; i < 2; ++i) {
      int c = tid + i * 256;
      int row = c >> 2, c8 = (c & 3) * 8;
      gld_lds16(Bb + (size_t)row * K + kk + c8, lB + c * 8);
    }
    __syncthreads();
    bf16x8 af[4], bfr[4];
#pragma unroll
    for (int mf = 0; mf < 4; ++mf)
      af[mf] = *(const bf16x8*)(lA + (wm + mf * 16 + lc) * 32 + lg * 8);
#pragma unroll
    for (int nf = 0; nf < 4; ++nf)
      bfr[nf] = *(const bf16x8*)(lB + (wn + nf * 16 + lc) * 32 + lg * 8);
#pragma unroll
    for (int mf = 0; mf < 4; ++mf)
#pragma unroll
      for (int nf = 0; nf < 4; ++nf)
        acc[mf][nf] = __builtin_amdgcn_mfma_f32_16x16x32_bf16(af[mf], bfr[nf], acc[mf][nf], 0, 0, 0);
    __syncthreads();
  }

  int lr = lg * 4;
  float bv[4];
#pragma unroll
  for (int nf = 0; nf < 4; ++nf) bv[nf] = bias[n0 + wn + nf * 16 + lc];
#pragma unroll
  for (int mf = 0; mf < 4; ++mf)
#pragma unroll
    for (int nf = 0; nf < 4; ++nf)
#pragma unroll
      for (int rr = 0; rr < 4; ++rr) {
        size_t gm = m0 + wm + mf * 16 + lr + rr;
        size_t gn = n0 + wn + nf * 16 + lc;
        float v = acc[mf][nf][rr] + bv[nf];
        if (OUT_BF16)
          ((unsigned short*)C)[gm * N + gn] = f2bf(v);
        else
          ((float*)C)[gm * N + gn] = v;
      }
}

// ---------------- flash attention ----------------
// grid: 1024 wgs = b(2) x h(16) x qtile(32).  4 waves/wg, 16 q-rows/wave, KVBLK=64.
// K/V tiles staged in LDS (double-buffered, XOR-swizzled via pre-swizzled
// global source; rule #21), shared by all 4 waves.
// LDS = 2*8K(K) + 2*8K(V) + 8K(P) = 40960 B -> 4 WGs/CU.
__launch_bounds__(256, 4)
__global__ void k_attn(const unsigned short* __restrict__ qkv,
                       const unsigned short* __restrict__ vt,
                       const float* __restrict__ mask,
                       unsigned short* __restrict__ ao) {
  __shared__ unsigned short lK[2][64 * 64];
  __shared__ unsigned short lV[2][64 * 64];
  __shared__ unsigned short lP[64 * 64];
  int wg = blockIdx.x;
  int b = wg >> 9, r0 = wg & 511, h = r0 >> 5, qt = r0 & 31;
  int tid = threadIdx.x, w = tid >> 6, l = tid & 63;
  int lg = l >> 4, lc = l & 15;
  int q0 = qt * 64 + w * 16;  // batch-local q base of this wave

  const unsigned short* Qb = qkv + (size_t)(b * 2048 + q0) * 3072 + h * 64;
  const unsigned short* Kb = qkv + (size_t)(b * 2048) * 3072 + 1024 + h * 64;
  const unsigned short* Vb = vt + (size_t)((b * 16 + h) * 64) * 2048;

  // staging geometry: chunk (i*4+w) covers LDS bytes chunk*1024 + l*16.
  // physical row r = i*32 + w*8 + (l>>3); logical col = ((l&7)^(l>>3))*8 elems
  // (inverse of byte-swizzle  phys = row*128 + (cb ^ ((row&7)<<4)) ).
  int rsub = l >> 3;
  int scol = ((l & 7) ^ rsub) * 8;

  bf16x8 qf[2];
#pragma unroll
  for (int ks = 0; ks < 2; ++ks)
    qf[ks] = *(const bf16x8*)(Qb + (size_t)lc * 3072 + ks * 32 + lg * 8);

  const float* mrow[4];
#pragma unroll
  for (int rr = 0; rr < 4; ++rr)
    mrow[rr] = mask + (size_t)(q0 + lg * 4 + rr) * 2048 + lc;

  f32x4 o[4] = {};
  float m[4], ll[4];
#pragma unroll
  for (int rr = 0; rr < 4; ++rr) { m[rr] = -1e30f; ll[rr] = 0.f; }

  // prologue: stage tile 0 into buf 0
#pragma unroll
  for (int i = 0; i < 2; ++i) {
    int r = i * 32 + w * 8 + rsub;
    gld_lds16(Kb + (size_t)r * 3072 + scol, &lK[0][(i * 4 + w) * 512]);
    gld_lds16(Vb + (size_t)r * 2048 + scol, &lV[0][(i * 4 + w) * 512]);
  }
  __syncthreads();

  int cur = 0;
  for (int t = 0; t < 32; ++t) {
    int k0 = t * 64;
    // stage next tile into buf cur^1 (async; drains at end-of-iter barrier)
    if (t < 31) {
#pragma unroll
      for (int i = 0; i < 2; ++i) {
        int r = i * 32 + w * 8 + rsub;
        gld_lds16(Kb + (size_t)(k0 + 64 + r) * 3072 + scol, &lK[cur ^ 1][(i * 4 + w) * 512]);
        gld_lds16(Vb + (size_t)r * 2048 + k0 + 64 + scol, &lV[cur ^ 1][(i * 4 + w) * 512]);
      }
    }
    const unsigned short* lKc = lK[cur];
    const unsigned short* lVc = lV[cur];

    // S = Q @ K^T  (kf rows = key idx, k-contig; swizzled read)
    f32x4 s[4] = {};
#pragma unroll
    for (int ks = 0; ks < 2; ++ks) {
      bf16x8 kf[4];
#pragma unroll
      for (int nf = 0; nf < 4; ++nf)
        kf[nf] = *(const bf16x8*)(lKc + (nf * 16 + lc) * 64 +
                                  ((ks * 32 + lg * 8) ^ ((lc & 7) << 3)));
#pragma unroll
      for (int nf = 0; nf < 4; ++nf)
        s[nf] = __builtin_amdgcn_mfma_f32_16x16x32_bf16(qf[ks], kf[nf], s[nf], 0, 0, 0);
    }

    // scale + mask
    float sv[4][4];
#pragma unroll
    for (int nf = 0; nf < 4; ++nf)
#pragma unroll
      for (int rr = 0; rr < 4; ++rr)
        sv[nf][rr] = s[nf][rr] * 0.125f + mrow[rr][k0 + nf * 16];

    // online softmax (row spans 16 lanes (lc) x 4 regs (nf))
    float al[4], mn[4];
#pragma unroll
    for (int rr = 0; rr < 4; ++rr) {
      float t2 = fmaxf(fmaxf(sv[0][rr], sv[1][rr]), fmaxf(sv[2][rr], sv[3][rr]));
      t2 = fmaxf(t2, __shfl_xor(t2, 1));
      t2 = fmaxf(t2, __shfl_xor(t2, 2));
      t2 = fmaxf(t2, __shfl_xor(t2, 4));
      t2 = fmaxf(t2, __shfl_xor(t2, 8));
      mn[rr] = fmaxf(m[rr], t2);
      al[rr] = __expf(m[rr] - mn[rr]);
      m[rr] = mn[rr];
    }
    float ps[4] = {0.f, 0.f, 0.f, 0.f};
#pragma unroll
    for (int nf = 0; nf < 4; ++nf)
#pragma unroll
      for (int rr = 0; rr < 4; ++rr) {
        float p = __expf(sv[nf][rr] - mn[rr]);
        ps[rr] += p;
        int prow = w * 16 + lg * 4 + rr;
        lP[prow * 64 + ((nf * 16 + lc) ^ ((prow & 7) << 3))] = f2bf(p);
      }
#pragma unroll
    for (int rr = 0; rr < 4; ++rr) {
      float t2 = ps[rr];
      t2 += __shfl_xor(t2, 1);
      t2 += __shfl_xor(t2, 2);
      t2 += __shfl_xor(t2, 4);
      t2 += __shfl_xor(t2, 8);
      ll[rr] = ll[rr] * al[rr] + t2;
    }
#pragma unroll
    for (int nf = 0; nf < 4; ++nf)
#pragma unroll
      for (int rr = 0; rr < 4; ++rr) o[nf][rr] *= al[rr];

    // O += P @ V  (pa from wave-private swizzled lP rows; vf from swizzled lV)
#pragma unroll
    for (int ks2 = 0; ks2 < 2; ++ks2) {
      bf16x8 pa = *(const bf16x8*)(lP + (w * 16 + lc) * 64 +
                                   ((ks2 * 32 + lg * 8) ^ ((lc & 7) << 3)));
      bf16x8 vf[4];
#pragma unroll
      for (int nf = 0; nf < 4; ++nf)
        vf[nf] = *(const bf16x8*)(lVc + (nf * 16 + lc) * 64 +
                                  ((ks2 * 32 + lg * 8) ^ ((lc & 7) << 3)));
#pragma unroll
      for (int nf = 0; nf < 4; ++nf)
        o[nf] = __builtin_amdgcn_mfma_f32_16x16x32_bf16(pa, vf[nf], o[nf], 0, 0, 0);
    }

    __syncthreads();  // drains stage (vmcnt) + protects buffer swap
    cur ^= 1;
  }

#pragma unroll
  for (int rr = 0; rr < 4; ++rr) {
    float inv = 1.f / ll[rr];
    int q = q0 + lg * 4 + rr;
#pragma unroll
    for (int nf = 0; nf < 4; ++nf)
      ao[(size_t)(b * 2048 + q) * 1024 + h * 64 + nf * 16 + lc] = f2bf(o[nf][rr] * inv);
  }
}

// ---------------- launch ----------------
extern "C" void kernel_launch(void* const* d_in, const int* in_sizes, int n_in,
                              void* d_out, int out_size, void* d_ws, size_t ws_size,
                              hipStream_t stream) {
  const float* batch = (const float*)d_in[0];
  const float* mask = (const float*)d_in[1];
  const float* Wq = (const float*)d_in[2];
  const float* Wk = (const float*)d_in[3];
  const float* Wv = (const float*)d_in[4];
  const float* bq = (const float*)d_in[5];
  const float* bk = (const float*)d_in[6];
  const float* bvv = (const float*)d_in[7];
  const float* Wo = (const float*)d_in[8];
  const float* bo = (const float*)d_in[9];

  char* ws = (char*)d_ws;
  unsigned short* Xb    = (unsigned short*)(ws);                 //  8,388,608
  unsigned short* WqkvT = (unsigned short*)(ws + 8388608);       //  6,291,456
  unsigned short* WoT   = (unsigned short*)(ws + 14680064);      //  2,097,152
  float*          bcat  = (float*)(ws + 16777216);               //     12,288
  unsigned short* QKV   = (unsigned short*)(ws + 16789504);      // 25,165,824
  unsigned short* Vt    = (unsigned short*)(ws + 41955328);      //  8,388,608
  unsigned short* AO    = (unsigned short*)(ws + 50343936);      //  8,388,608

  hipLaunchKernelGGL(k_cvt_x, dim3(4096), dim3(256), 0, stream, batch, Xb);
  hipLaunchKernelGGL(k_wt, dim3(4096), dim3(256), 0, stream, Wq, Wk, Wv, Wo, WqkvT, WoT);
  hipLaunchKernelGGL(k_bias, dim3(12), dim3(256), 0, stream, bq, bk, bvv, bcat);
  hipLaunchKernelGGL((k_gemm<1>), dim3(24, 32), dim3(256), 0, stream,
                     Xb, WqkvT, bcat, (void*)QKV, 4096, 3072, 1024);
  hipLaunchKernelGGL(k_vt, dim3(32, 32), dim3(256), 0, stream, QKV, Vt);
  hipLaunchKernelGGL(k_attn, dim3(1024), dim3(256), 0, stream, QKV, Vt, mask, AO);
  hipLaunchKernelGGL((k_gemm<0>), dim3(8, 32), dim3(256), 0, stream,
                     AO, WoT, bo, (void*)d_out, 4096, 1024, 1024);
}

// Round 3
// 259.977 us; speedup vs baseline: 1.6075x; 1.0761x over previous
//
#include <hip/hip_runtime.h>
#include <hip/hip_bf16.h>

typedef __attribute__((ext_vector_type(8))) short bf16x8;
typedef __attribute__((ext_vector_type(4))) float f32x4;
typedef __attribute__((ext_vector_type(4))) unsigned short u16x4;
typedef __attribute__((ext_vector_type(8))) unsigned short u16x8;

#define DEVI static __device__ __forceinline__

DEVI unsigned short f2bf(float f) {
  union { __hip_bfloat16 h; unsigned short u; } cv;
  cv.h = __float2bfloat16(f);
  return cv.u;
}

DEVI float bf2f(unsigned short u) {
  union { unsigned int i; float f; } cv;
  cv.i = (unsigned int)u << 16;
  return cv.f;
}

DEVI void gld_lds16(const unsigned short* g, unsigned short* l) {
  __builtin_amdgcn_global_load_lds(
      (const __attribute__((address_space(1))) unsigned int*)g,
      (__attribute__((address_space(3))) unsigned int*)l, 16, 0, 0);
}

// ---------------- prep kernels ----------------

__global__ void k_cvt_x(const float* __restrict__ x, unsigned short* __restrict__ xb) {
  int i = blockIdx.x * 256 + threadIdx.x;
  f32x4 v = *((const f32x4*)x + i);
  u16x4 o;
#pragma unroll
  for (int j = 0; j < 4; ++j) o[j] = f2bf(v[j]);
  *((u16x4*)xb + i) = o;
}

// W[g][k][n] f32 -> Wt[g][n][k] bf16 via 32x32 LDS tiles. 4096 blocks.
__global__ void k_wt(const float* __restrict__ Wq, const float* __restrict__ Wk,
                     const float* __restrict__ Wv, const float* __restrict__ Wo,
                     unsigned short* __restrict__ wqkvT, unsigned short* __restrict__ woT) {
  __shared__ float lt[32][33];
  int t = blockIdx.x;
  int g = t >> 10, r = t & 1023, kt = r >> 5, nt = r & 31;
  const float* W = (g == 0) ? Wq : (g == 1) ? Wk : (g == 2) ? Wv : Wo;
  unsigned short* out = (g < 3) ? (wqkvT + (size_t)g * 1024 * 1024) : woT;
  int tid = threadIdx.x;
  int row = tid >> 3, c4 = tid & 7;
  f32x4 v = *(const f32x4*)(W + (size_t)(kt * 32 + row) * 1024 + nt * 32 + c4 * 4);
#pragma unroll
  for (int j = 0; j < 4; ++j) lt[row][c4 * 4 + j] = v[j];
  __syncthreads();
  u16x4 o;
#pragma unroll
  for (int j = 0; j < 4; ++j) o[j] = f2bf(lt[c4 * 4 + j][row]);
  *(u16x4*)(out + (size_t)(nt * 32 + row) * 1024 + kt * 32 + c4 * 4) = o;
}

__global__ void k_bias(const float* __restrict__ bq, const float* __restrict__ bk,
                       const float* __restrict__ bv, float* __restrict__ bcat) {
  int i = blockIdx.x * 256 + threadIdx.x;
  if (i < 3072) bcat[i] = (i < 1024) ? bq[i] : (i < 2048) ? bk[i - 1024] : bv[i - 2048];
}

// mask[q][k] f32 -> mU[k>>2][q][k&3] = bf16(mask * log2e). grid (64,64).
// Layout gives attn one coalesced b64 load per 4 consecutive keys.
__global__ void k_mt(const float* __restrict__ mask, unsigned short* __restrict__ mU) {
  __shared__ float lt[32][33];
  int q0 = blockIdx.y * 32, k0 = blockIdx.x * 32;
  int tid = threadIdx.x;
  int row = tid >> 3, c4 = tid & 7;
  f32x4 v = *(const f32x4*)(mask + (size_t)(q0 + row) * 2048 + k0 + c4 * 4);
#pragma unroll
  for (int j = 0; j < 4; ++j) lt[row][c4 * 4 + j] = v[j] * 1.4426950408889634f;
  __syncthreads();
  int kq = tid >> 5, qr = tid & 31;
  u16x4 o;
#pragma unroll
  for (int j = 0; j < 4; ++j) o[j] = f2bf(lt[qr][kq * 4 + j]);
  *(u16x4*)(mU + ((size_t)(k0 >> 2) + kq) * 8192 + (size_t)(q0 + qr) * 4) = o;
}

// transpose V slice of QKV -> Vt[(b*16+h)*64 + d][s]  (bf16)
__global__ void k_vt(const unsigned short* __restrict__ qkv, unsigned short* __restrict__ vt) {
  __shared__ unsigned short lt[64][72];
  int bh = blockIdx.y, s0 = blockIdx.x * 64;
  int b = bh >> 4, h = bh & 15;
  int tid = threadIdx.x;
#pragma unroll
  for (int i = 0; i < 2; ++i) {
    int c = tid + i * 256;
    int row = c >> 3, c8 = (c & 7) * 8;
    u16x8 v = *(const u16x8*)(qkv + (size_t)(b * 2048 + s0 + row) * 3072 + 2048 + h * 64 + c8);
#pragma unroll
    for (int j = 0; j < 8; ++j) lt[row][c8 + j] = v[j];
  }
  __syncthreads();
#pragma unroll
  for (int i = 0; i < 2; ++i) {
    int c = tid + i * 256;
    int d = c >> 3, s8 = (c & 7) * 8;
    u16x8 o;
#pragma unroll
    for (int j = 0; j < 8; ++j) o[j] = lt[s8 + j][d];
    *(u16x8*)(vt + (size_t)(bh * 64 + d) * 2048 + s0 + s8) = o;
  }
}

// ---------------- GEMM: C[M][N] = A[M][K](bf16) @ Bt[N][K](bf16)^T + bias ----------------
template <int OUT_BF16>
__launch_bounds__(256)
__global__ void k_gemm(const unsigned short* __restrict__ A,
                       const unsigned short* __restrict__ Bt,
                       const float* __restrict__ bias, void* __restrict__ C,
                       int M, int N, int K) {
  __shared__ unsigned short lA[128 * 32];
  __shared__ unsigned short lB[128 * 32];
  int tid = threadIdx.x;
  int m0 = blockIdx.y * 128, n0 = blockIdx.x * 128;
  int w = tid >> 6, l = tid & 63;
  int wm = (w >> 1) * 64, wn = (w & 1) * 64;
  int lg = l >> 4, lc = l & 15;
  f32x4 acc[4][4] = {};
  const unsigned short* Ab = A + (size_t)m0 * K;
  const unsigned short* Bb = Bt + (size_t)n0 * K;

  for (int kk = 0; kk < K; kk += 32) {
#pragma unroll
    for (int i = 0; i < 2; ++i) {
      int c = tid + i * 256;
      int row = c >> 2, c8 = (c & 3) * 8;
      gld_lds16(Ab + (size_t)row * K + kk + c8, lA + c * 8);
    }
#pragma unroll
    for (int i = 0; i < 2; ++i) {
      int c = tid + i * 256;
      int row = c >> 2, c8 = (c & 3) * 8;
      gld_lds16(Bb + (size_t)row * K + kk + c8, lB + c * 8);
    }
    __syncthreads();
    bf16x8 af[4], bfr[4];
#pragma unroll
    for (int mf = 0; mf < 4; ++mf)
      af[mf] = *(const bf16x8*)(lA + (wm + mf * 16 + lc) * 32 + lg * 8);
#pragma unroll
    for (int nf = 0; nf < 4; ++nf)
      bfr[nf] = *(const bf16x8*)(lB + (wn + nf * 16 + lc) * 32 + lg * 8);
#pragma unroll
    for (int mf = 0; mf < 4; ++mf)
#pragma unroll
      for (int nf = 0; nf < 4; ++nf)
        acc[mf][nf] = __builtin_amdgcn_mfma_f32_16x16x32_bf16(af[mf], bfr[nf], acc[mf][nf], 0, 0, 0);
    __syncthreads();
  }

  int lr = lg * 4;
  float bv[4];
#pragma unroll
  for (int nf = 0; nf < 4; ++nf) bv[nf] = bias[n0 + wn + nf * 16 + lc];
#pragma unroll
  for (int mf = 0; mf < 4; ++mf)
#pragma unroll
    for (int nf = 0; nf < 4; ++nf)
#pragma unroll
      for (int rr = 0; rr < 4; ++rr) {
        size_t gm = m0 + wm + mf * 16 + lr + rr;
        size_t gn = n0 + wn + nf * 16 + lc;
        float v = acc[mf][nf][rr] + bv[nf];
        if (OUT_BF16)
          ((unsigned short*)C)[gm * N + gn] = f2bf(v);
        else
          ((float*)C)[gm * N + gn] = v;
      }
}

// ---------------- flash attention (swapped-operand, in-lane softmax) ----------------
// grid: 1024 wgs = b(2) x h(16) x qtile(32), XCD-chunked swizzle.
// 4 waves/wg, 16 q-rows/wave (q = lane&15), KVBLK=64.
// s = mfma(K,Q): lane holds S[key = blk*16+lg*4+rr][q=lc] -> softmax in-lane,
// only 2 shfl per tile (max); sum fully deferred to per-lane partials.
// o = mfma(V^T,P): lane holds O[d = nf*16+lg*4+rr][q=lc] -> rescale in-lane.
__launch_bounds__(256, 4)
__global__ void k_attn(const unsigned short* __restrict__ qkv,
                       const unsigned short* __restrict__ vt,
                       const unsigned short* __restrict__ mU,
                       unsigned short* __restrict__ ao) {
  __shared__ unsigned short lK[2][64 * 64];
  __shared__ unsigned short lV[2][64 * 64];
  __shared__ unsigned short lP[64 * 64];
  int wg0 = blockIdx.x;
  int wg = (wg0 & 7) * 128 + (wg0 >> 3);  // XCD chunking: same (b,h) stays on one XCD
  int b = wg >> 9, r0 = wg & 511, h = r0 >> 5, qt = r0 & 31;
  int tid = threadIdx.x, w = tid >> 6, l = tid & 63;
  int lg = l >> 4, lc = l & 15;
  int c = lc & 7;
  int q0 = qt * 64 + w * 16;  // batch-local q base of this wave

  const unsigned short* Qb = qkv + (size_t)(b * 2048 + q0) * 3072 + h * 64;
  const unsigned short* Kb = qkv + (size_t)(b * 2048) * 3072 + 1024 + h * 64;
  const unsigned short* Vb = vt + (size_t)((b * 16 + h) * 64) * 2048;
  // mask base: this lane's q column + its lg word-row offset
  const unsigned short* mUb = mU + (size_t)lg * 8192 + (size_t)(q0 + lc) * 4;

  // staging geometry (same as r2; verified conflict-free + correct)
  int rsub = l >> 3;
  int scol = ((l & 7) ^ rsub) * 8;

  bf16x8 qf[2];
#pragma unroll
  for (int ks = 0; ks < 2; ++ks)
    qf[ks] = *(const bf16x8*)(Qb + (size_t)lc * 3072 + ks * 32 + lg * 8);

  f32x4 o2[4] = {};
  float m = -1e30f, ll = 0.f;

  // prologue: stage tile 0 into buf 0
#pragma unroll
  for (int i = 0; i < 2; ++i) {
    int r = i * 32 + w * 8 + rsub;
    gld_lds16(Kb + (size_t)r * 3072 + scol, &lK[0][(i * 4 + w) * 512]);
    gld_lds16(Vb + (size_t)r * 2048 + scol, &lV[0][(i * 4 + w) * 512]);
  }
  __syncthreads();

  int cur = 0;
  unsigned short* lPw = lP + (w * 16 + lc) * 64;  // wave-private P row for this lane
  for (int t = 0; t < 32; ++t) {
    int k0 = t * 64;
    if (t < 31) {
#pragma unroll
      for (int i = 0; i < 2; ++i) {
        int r = i * 32 + w * 8 + rsub;
        gld_lds16(Kb + (size_t)(k0 + 64 + r) * 3072 + scol, &lK[cur ^ 1][(i * 4 + w) * 512]);
        gld_lds16(Vb + (size_t)r * 2048 + k0 + 64 + scol, &lV[cur ^ 1][(i * 4 + w) * 512]);
      }
    }
    const unsigned short* lKc = lK[cur];
    const unsigned short* lVc = lV[cur];

    // S^T = K @ Q^T : s[blk][rr] = S[key=blk*16+lg*4+rr][q=lc]
    f32x4 s[4] = {};
#pragma unroll
    for (int ks = 0; ks < 2; ++ks) {
      bf16x8 kf[4];
#pragma unroll
      for (int blk = 0; blk < 4; ++blk)
        kf[blk] = *(const bf16x8*)(lKc + (blk * 16 + lc) * 64 +
                                   ((ks * 32 + lg * 8) ^ (c << 3)));
#pragma unroll
      for (int blk = 0; blk < 4; ++blk)
        s[blk] = __builtin_amdgcn_mfma_f32_16x16x32_bf16(kf[blk], qf[ks], s[blk], 0, 0, 0);
    }

    // logits in log2-space: tl = s * (0.125*log2e) + mask*log2e  (mask pre-scaled)
    float tl[16];
#pragma unroll
    for (int blk = 0; blk < 4; ++blk) {
      u16x4 mv = *(const u16x4*)(mUb + ((size_t)(k0 >> 2) + blk * 4) * 8192);
#pragma unroll
      for (int rr = 0; rr < 4; ++rr)
        tl[blk * 4 + rr] = fmaf(s[blk][rr], 0.18033688011112042f, bf2f(mv[rr]));
    }

    // in-lane max tree + 2 cross-group shfl
    float tm[8];
#pragma unroll
    for (int i = 0; i < 8; ++i) tm[i] = fmaxf(tl[2 * i], tl[2 * i + 1]);
#pragma unroll
    for (int i = 0; i < 4; ++i) tm[i] = fmaxf(tm[2 * i], tm[2 * i + 1]);
    float mx = fmaxf(fmaxf(tm[0], tm[1]), fmaxf(tm[2], tm[3]));
    mx = fmaxf(mx, __shfl_xor(mx, 16));
    mx = fmaxf(mx, __shfl_xor(mx, 32));
    float mn = fmaxf(m, mx);
    float al = exp2f(m - mn);
    m = mn;

    // p = 2^(tl - mn); per-lane partial sum (cross-lane reduce deferred to epilogue)
    float psum = 0.f;
#pragma unroll
    for (int blk = 0; blk < 4; ++blk) {
      u16x4 pk;
#pragma unroll
      for (int rr = 0; rr < 4; ++rr) {
        float p = exp2f(tl[blk * 4 + rr] - mn);
        psum += p;
        pk[rr] = f2bf(p);
      }
      *(u16x4*)(lPw + (((blk * 32 + lg * 8) ^ (c << 4)) >> 1)) = pk;
    }
    ll = ll * al + psum;
#pragma unroll
    for (int nf = 0; nf < 4; ++nf)
#pragma unroll
      for (int rr = 0; rr < 4; ++rr) o2[nf][rr] *= al;

    // O^T += V^T @ P^T : o2[nf] row d = nf*16+lg*4+rr, col q = lc
#pragma unroll
    for (int ks2 = 0; ks2 < 2; ++ks2) {
      bf16x8 pa = *(const bf16x8*)(lPw + (((ks2 * 64 + lg * 16) ^ (c << 4)) >> 1));
      bf16x8 vf[4];
#pragma unroll
      for (int nf = 0; nf < 4; ++nf)
        vf[nf] = *(const bf16x8*)(lVc + (nf * 16 + lc) * 64 +
                                  ((ks2 * 32 + lg * 8) ^ (c << 3)));
#pragma unroll
      for (int nf = 0; nf < 4; ++nf)
        o2[nf] = __builtin_amdgcn_mfma_f32_16x16x32_bf16(vf[nf], pa, o2[nf], 0, 0, 0);
    }

    __syncthreads();  // drains stage (vmcnt) + protects K/V buffer swap
    cur ^= 1;
  }

  // epilogue: finish row-sum, normalize, transpose O via wave-private LDS slice
  ll += __shfl_xor(ll, 16);
  ll += __shfl_xor(ll, 32);
  float inv = 1.f / ll;
#pragma unroll
  for (int nf = 0; nf < 4; ++nf) {
    u16x4 pk;
#pragma unroll
    for (int rr = 0; rr < 4; ++rr) pk[rr] = f2bf(o2[nf][rr] * inv);
    *(u16x4*)(lPw + (((nf * 32 + lg * 8) ^ (c << 4)) >> 1)) = pk;
  }
  // read back coalesced: lane l -> q row (l>>2), 2x 16B chunks
  int rq = l >> 2, seg = l & 3, c2 = rq & 7;
  const unsigned short* lPr = lP + (w * 16 + rq) * 64;
#pragma unroll
  for (int half = 0; half < 2; ++half) {
    u16x8 ov = *(const u16x8*)(lPr + (((seg * 32 + half * 16) ^ (c2 << 4)) >> 1));
    *(u16x8*)(ao + (size_t)(b * 2048 + q0 + rq) * 1024 + h * 64 + seg * 16 + half * 8) = ov;
  }
}

// ---------------- launch ----------------
extern "C" void kernel_launch(void* const* d_in, const int* in_sizes, int n_in,
                              void* d_out, int out_size, void* d_ws, size_t ws_size,
                              hipStream_t stream) {
  const float* batch = (const float*)d_in[0];
  const float* mask = (const float*)d_in[1];
  const float* Wq = (const float*)d_in[2];
  const float* Wk = (const float*)d_in[3];
  const float* Wv = (const float*)d_in[4];
  const float* bq = (const float*)d_in[5];
  const float* bk = (const float*)d_in[6];
  const float* bvv = (const float*)d_in[7];
  const float* Wo = (const float*)d_in[8];
  const float* bo = (const float*)d_in[9];

  char* ws = (char*)d_ws;
  unsigned short* Xb    = (unsigned short*)(ws);                 //  8,388,608 (reused as mU after gemm1)
  unsigned short* WqkvT = (unsigned short*)(ws + 8388608);       //  6,291,456
  unsigned short* WoT   = (unsigned short*)(ws + 14680064);      //  2,097,152
  float*          bcat  = (float*)(ws + 16777216);               //     12,288
  unsigned short* QKV   = (unsigned short*)(ws + 16789504);      // 25,165,824
  unsigned short* Vt    = (unsigned short*)(ws + 41955328);      //  8,388,608
  unsigned short* AO    = (unsigned short*)(ws + 50343936);      //  8,388,608
  unsigned short* mU    = Xb;  // alias: Xb dead after k_gemm<1>

  hipLaunchKernelGGL(k_cvt_x, dim3(4096), dim3(256), 0, stream, batch, Xb);
  hipLaunchKernelGGL(k_wt, dim3(4096), dim3(256), 0, stream, Wq, Wk, Wv, Wo, WqkvT, WoT);
  hipLaunchKernelGGL(k_bias, dim3(12), dim3(256), 0, stream, bq, bk, bvv, bcat);
  hipLaunchKernelGGL((k_gemm<1>), dim3(24, 32), dim3(256), 0, stream,
                     Xb, WqkvT, bcat, (void*)QKV, 4096, 3072, 1024);
  hipLaunchKernelGGL(k_mt, dim3(64, 64), dim3(256), 0, stream, mask, mU);
  hipLaunchKernelGGL(k_vt, dim3(32, 32), dim3(256), 0, stream, QKV, Vt);
  hipLaunchKernelGGL(k_attn, dim3(1024), dim3(256), 0, stream, QKV, Vt, mU, AO);
  hipLaunchKernelGGL((k_gemm<0>), dim3(8, 32), dim3(256), 0, stream,
                     AO, WoT, bo, (void*)d_out, 4096, 1024, 1024);
}